// Round 1
// baseline (109.494 us; speedup 1.0000x reference)
//
#include <hip/hip_runtime.h>

// SparseArch: r0 = ids_0 % ZCH; r1 = ids_1 % ZCH;
// loss = mean(concat(table_0[r0], table_1[r1]))   over [2N, 64]
// d_out (float32): [loss (1)] [r0 as float (N)] [r1 as float (N)]

constexpr unsigned ZCH  = 2000000u;
constexpr int BLOCK = 256;
constexpr int GRID  = 2048;   // 524288 threads = 32768 row-groups of 16 lanes

__global__ __launch_bounds__(BLOCK) void gather_sum_kernel(
    const float* __restrict__ t0, const float* __restrict__ t1,
    const int*  __restrict__ ids0, const int* __restrict__ ids1,
    float* __restrict__ out, int n, double* __restrict__ partial)
{
    const int tid    = blockIdx.x * BLOCK + (int)threadIdx.x;
    const int sub    = tid & 15;          // lane within 16-thread row-group
    const int group  = tid >> 4;          // row-group id
    const int ngroups = (GRID * BLOCK) >> 4;
    const int total  = 2 * n;

    float acc = 0.f;
    for (int row = group; row < total; row += ngroups) {
        const bool f1 = (row >= n);
        const int  i  = f1 ? (row - n) : row;
        const int  id = f1 ? ids1[i] : ids0[i];
        const unsigned r = (unsigned)id % ZCH;
        const float* tab = f1 ? t1 : t0;
        // 16 lanes x float4 = 256 B = one full row, coalesced & 256B-aligned
        const float4 v = *reinterpret_cast<const float4*>(tab + (size_t)r * 64u + (unsigned)sub * 4u);
        acc += (v.x + v.y) + (v.z + v.w);
        if (sub == 0) out[1 + row] = (float)r;   // remapped id, exact in fp32
    }

    // wave64 reduce
    #pragma unroll
    for (int off = 32; off > 0; off >>= 1)
        acc += __shfl_down(acc, off, 64);

    __shared__ double sacc[BLOCK / 64];
    if ((threadIdx.x & 63) == 0) sacc[threadIdx.x >> 6] = (double)acc;
    __syncthreads();
    if (threadIdx.x == 0) {
        double s = 0.0;
        #pragma unroll
        for (int w = 0; w < BLOCK / 64; ++w) s += sacc[w];
        partial[blockIdx.x] = s;   // every block writes its slot -> no ws zeroing needed
    }
}

__global__ __launch_bounds__(256) void finalize_kernel(
    const double* __restrict__ partial, float* __restrict__ out, int n)
{
    __shared__ double sacc[256];
    double s = 0.0;
    for (int i = (int)threadIdx.x; i < GRID; i += 256) s += partial[i];
    sacc[threadIdx.x] = s;
    __syncthreads();
    for (int off = 128; off > 0; off >>= 1) {
        if ((int)threadIdx.x < off) sacc[threadIdx.x] += sacc[threadIdx.x + off];
        __syncthreads();
    }
    if (threadIdx.x == 0)
        out[0] = (float)(sacc[0] / ((double)n * 128.0));   // 2N * 64 elements
}

extern "C" void kernel_launch(void* const* d_in, const int* in_sizes, int n_in,
                              void* d_out, int out_size, void* d_ws, size_t ws_size,
                              hipStream_t stream)
{
    const float* t0   = (const float*)d_in[0];
    const float* t1   = (const float*)d_in[1];
    const int*   ids0 = (const int*)d_in[2];
    const int*   ids1 = (const int*)d_in[3];
    float* out = (float*)d_out;
    const int n = in_sizes[2];            // NUM_IDS per feature

    double* partial = (double*)d_ws;      // GRID doubles = 16 KB scratch

    gather_sum_kernel<<<GRID, BLOCK, 0, stream>>>(t0, t1, ids0, ids1, out, n, partial);
    finalize_kernel<<<1, 256, 0, stream>>>(partial, out, n);
}

// Round 2
// 96.682 us; speedup vs baseline: 1.1325x; 1.1325x over previous
//
#include <hip/hip_runtime.h>

// SparseArch: r0 = ids_0 % ZCH; r1 = ids_1 % ZCH;
// loss = mean(concat(table_0[r0], table_1[r1]))   over [2N, 64]
// d_out (float32): [loss (1)] [r0 as float (N)] [r1 as float (N)]

constexpr unsigned ZCH  = 2000000u;
constexpr int BLOCK = 256;
constexpr int GRID  = 2048;   // 524288 threads = 32768 row-groups of 16 lanes

__global__ __launch_bounds__(BLOCK) void gather_sum_kernel(
    const float* __restrict__ t0, const float* __restrict__ t1,
    const int*  __restrict__ ids0, const int* __restrict__ ids1,
    float* __restrict__ out, int n, double* __restrict__ partial)
{
    const int tid     = blockIdx.x * BLOCK + (int)threadIdx.x;
    const int sub     = tid & 15;          // lane within 16-thread row-group
    const int group   = tid >> 4;          // row-group id
    const int ngroups = (GRID * BLOCK) >> 4;
    const unsigned soff = (unsigned)sub * 4u;

    float acc = 0.f;
    // Each group handles index i for BOTH features: 2 independent id loads,
    // then 2 independent 256B row loads -> 2x memory-level parallelism,
    // no feature-select branch.
    #pragma unroll 2
    for (int i = group; i < n; i += ngroups) {
        const int id0 = ids0[i];
        const int id1 = ids1[i];
        const unsigned r0 = (unsigned)id0 % ZCH;
        const unsigned r1 = (unsigned)id1 % ZCH;
        const float4 v0 = *reinterpret_cast<const float4*>(t0 + (size_t)(r0 * 64u + soff));
        const float4 v1 = *reinterpret_cast<const float4*>(t1 + (size_t)(r1 * 64u + soff));
        acc += ((v0.x + v0.y) + (v0.z + v0.w)) + ((v1.x + v1.y) + (v1.z + v1.w));
        if (sub == 0) {
            out[1 + i]     = (float)r0;    // exact in fp32 (r < 2^21)
            out[1 + n + i] = (float)r1;
        }
    }

    // wave64 reduce
    #pragma unroll
    for (int off = 32; off > 0; off >>= 1)
        acc += __shfl_down(acc, off, 64);

    __shared__ double sacc[BLOCK / 64];
    if ((threadIdx.x & 63) == 0) sacc[threadIdx.x >> 6] = (double)acc;
    __syncthreads();
    if (threadIdx.x == 0) {
        double s = 0.0;
        #pragma unroll
        for (int w = 0; w < BLOCK / 64; ++w) s += sacc[w];
        partial[blockIdx.x] = s;   // every block writes its slot each launch
    }
}

__global__ __launch_bounds__(256) void finalize_kernel(
    const double* __restrict__ partial, float* __restrict__ out, int n)
{
    __shared__ double sacc[256];
    double s = 0.0;
    for (int i = (int)threadIdx.x; i < GRID; i += 256) s += partial[i];
    sacc[threadIdx.x] = s;
    __syncthreads();
    for (int off = 128; off > 0; off >>= 1) {
        if ((int)threadIdx.x < off) sacc[threadIdx.x] += sacc[threadIdx.x + off];
        __syncthreads();
    }
    if (threadIdx.x == 0)
        out[0] = (float)(sacc[0] / ((double)n * 128.0));   // 2N * 64 elements
}

extern "C" void kernel_launch(void* const* d_in, const int* in_sizes, int n_in,
                              void* d_out, int out_size, void* d_ws, size_t ws_size,
                              hipStream_t stream)
{
    const float* t0   = (const float*)d_in[0];
    const float* t1   = (const float*)d_in[1];
    const int*   ids0 = (const int*)d_in[2];
    const int*   ids1 = (const int*)d_in[3];
    float* out = (float*)d_out;
    const int n = in_sizes[2];            // NUM_IDS per feature

    double* partial = (double*)d_ws;      // GRID doubles = 16 KB scratch

    gather_sum_kernel<<<GRID, BLOCK, 0, stream>>>(t0, t1, ids0, ids1, out, n, partial);
    finalize_kernel<<<1, 256, 0, stream>>>(partial, out, n);
}

// Round 3
// 96.223 us; speedup vs baseline: 1.1379x; 1.0048x over previous
//
#include <hip/hip_runtime.h>

// SparseArch: r0 = ids_0 % ZCH; r1 = ids_1 % ZCH;
// loss = mean(concat(table_0[r0], table_1[r1]))   over [2N, 64]
// d_out (float32): [loss (1)] [r0 as float (N)] [r1 as float (N)]

constexpr unsigned ZCH  = 2000000u;
constexpr int BLOCK = 256;
constexpr int GRID  = 2048;   // 524288 threads = 32768 row-groups of 16 lanes

__global__ __launch_bounds__(BLOCK) void gather_sum_kernel(
    const float* __restrict__ t0, const float* __restrict__ t1,
    const int*  __restrict__ ids0, const int* __restrict__ ids1,
    float* __restrict__ out, int n, double* __restrict__ partial)
{
    const int tid     = blockIdx.x * BLOCK + (int)threadIdx.x;
    const int sub     = tid & 15;          // lane within 16-thread row-group
    const int group   = tid >> 4;          // row-group id
    const int ngroups = (GRID * BLOCK) >> 4;

    // Hoist the lane offset into the base pointers: per-iteration address is
    // base + r*256B, a single 32-bit shift-add.
    const float* __restrict__ b0 = t0 + (unsigned)sub * 4u;
    const float* __restrict__ b1 = t1 + (unsigned)sub * 4u;

    float acc = 0.f;
    // 4-deep unroll: 8 independent id loads + 8 independent 256B row loads
    // in flight per thread -> enough MLP to cover ~900cy HBM latency.
    #pragma unroll 4
    for (int i = group; i < n; i += ngroups) {
        const int id0 = ids0[i];
        const int id1 = ids1[i];
        const unsigned r0 = (unsigned)id0 % ZCH;
        const unsigned r1 = (unsigned)id1 % ZCH;
        const float4 v0 = *reinterpret_cast<const float4*>(b0 + (size_t)r0 * 64u);
        const float4 v1 = *reinterpret_cast<const float4*>(b1 + (size_t)r1 * 64u);
        acc += ((v0.x + v0.y) + (v0.z + v0.w)) + ((v1.x + v1.y) + (v1.z + v1.w));
        if (sub == 0) {
            out[1 + i]     = (float)r0;    // exact in fp32 (r < 2^21)
            out[1 + n + i] = (float)r1;
        }
    }

    // wave64 reduce
    #pragma unroll
    for (int off = 32; off > 0; off >>= 1)
        acc += __shfl_down(acc, off, 64);

    __shared__ double sacc[BLOCK / 64];
    if ((threadIdx.x & 63) == 0) sacc[threadIdx.x >> 6] = (double)acc;
    __syncthreads();
    if (threadIdx.x == 0) {
        double s = 0.0;
        #pragma unroll
        for (int w = 0; w < BLOCK / 64; ++w) s += sacc[w];
        partial[blockIdx.x] = s;   // every block writes its slot each launch
    }
}

__global__ __launch_bounds__(256) void finalize_kernel(
    const double* __restrict__ partial, float* __restrict__ out, int n)
{
    __shared__ double sacc[256];
    double s = 0.0;
    for (int i = (int)threadIdx.x; i < GRID; i += 256) s += partial[i];
    sacc[threadIdx.x] = s;
    __syncthreads();
    for (int off = 128; off > 0; off >>= 1) {
        if ((int)threadIdx.x < off) sacc[threadIdx.x] += sacc[threadIdx.x + off];
        __syncthreads();
    }
    if (threadIdx.x == 0)
        out[0] = (float)(sacc[0] / ((double)n * 128.0));   // 2N * 64 elements
}

extern "C" void kernel_launch(void* const* d_in, const int* in_sizes, int n_in,
                              void* d_out, int out_size, void* d_ws, size_t ws_size,
                              hipStream_t stream)
{
    const float* t0   = (const float*)d_in[0];
    const float* t1   = (const float*)d_in[1];
    const int*   ids0 = (const int*)d_in[2];
    const int*   ids1 = (const int*)d_in[3];
    float* out = (float*)d_out;
    const int n = in_sizes[2];            // NUM_IDS per feature

    double* partial = (double*)d_ws;      // GRID doubles = 16 KB scratch

    gather_sum_kernel<<<GRID, BLOCK, 0, stream>>>(t0, t1, ids0, ids1, out, n, partial);
    finalize_kernel<<<1, 256, 0, stream>>>(partial, out, n);
}